// Round 1
// baseline (231.617 us; speedup 1.0000x reference)
//
#include <hip/hip_runtime.h>
#include <math.h>

// Reverse cumulative max (suffix max) along last dim.
// x: (8,1,2048,2048) fp32 -> 16384 rows of W=2048. One wave per row.
//
// Round 2 analysis: the register-blocked layout (lane owns 32 contiguous
// floats) made every global_load_dwordx4 touch 64 distinct 128B lines
// (8 KiB spread per instruction) -> address-issue bound at 2.47 TB/s with
// VALUBusy 7.6%. Fix: lane-strided layout. Lane l owns float4s {64k+l},
// so every load AND store instruction is one contiguous 1 KiB wave access.
// The suffix scan becomes: intra-float4 scan, then 8 independent 64-lane
// shuffle suffix-scans (one per chunk of 256 elements), then a serial
// right-to-left fold of chunk maxima. No LDS, no __syncthreads.

#define ROW_W 2048
#define LANES 64
#define F4_PER_ROW (ROW_W / 4)        // 512 float4 per row
#define CHUNKS (F4_PER_ROW / LANES)   // 8 float4 per lane, chunk = 256 floats
#define WAVES_PER_BLOCK 4

__global__ __launch_bounds__(256) void suffix_max_kernel(
    const float* __restrict__ x, float* __restrict__ out, int nrows) {
  const int wave = threadIdx.x >> 6;
  const int lane = threadIdx.x & 63;
  const int row  = blockIdx.x * WAVES_PER_BLOCK + wave;
  if (row >= nrows) return;

  const float4* __restrict__ rin  = (const float4*)(x   + (size_t)row * ROW_W);
  float4* __restrict__       rout = (float4*)      (out + (size_t)row * ROW_W);

  // Coalesced loads: instruction k reads float4s [64k, 64k+64) -> 1 KiB/instr.
  float4 v[CHUNKS];
#pragma unroll
  for (int k = 0; k < CHUNKS; ++k) v[k] = rin[LANES * k + lane];

  // 1) Suffix max inside each float4 (elements 4f..4f+3, right-to-left).
  float inc[CHUNKS];
#pragma unroll
  for (int k = 0; k < CHUNKS; ++k) {
    v[k].z = fmaxf(v[k].z, v[k].w);
    v[k].y = fmaxf(v[k].y, v[k].z);
    v[k].x = fmaxf(v[k].x, v[k].y);
    inc[k] = v[k].x;  // this lane's max of its float4 in chunk k
  }

  // 2) Eight independent 64-lane inclusive suffix scans (from the right).
  //    __shfl_down returns the caller's own value when lane+off >= width;
  //    fmaxf is idempotent so no predication needed.
#pragma unroll
  for (int off = 1; off < LANES; off <<= 1) {
#pragma unroll
    for (int k = 0; k < CHUNKS; ++k) {
      float o = __shfl_down(inc[k], off, LANES);
      inc[k] = fmaxf(inc[k], o);
    }
  }

  // Chunk totals (lane 0 of each scan holds the full chunk max), broadcast.
  float tot[CHUNKS];
#pragma unroll
  for (int k = 0; k < CHUNKS; ++k) tot[k] = __shfl(inc[k], 0, LANES);

  // Exclusive suffix within chunk = right neighbor's inclusive value.
  float excl[CHUNKS];
#pragma unroll
  for (int k = 0; k < CHUNKS; ++k) {
    float e = __shfl_down(inc[k], 1, LANES);
    excl[k] = (lane == 63) ? -INFINITY : e;
  }

  // 3) Serial fold across chunks, right to left. tail = max of chunks > k.
  float tail = -INFINITY;
#pragma unroll
  for (int k = CHUNKS - 1; k >= 0; --k) {
    const float e = fmaxf(excl[k], tail);
    v[k].x = fmaxf(v[k].x, e);
    v[k].y = fmaxf(v[k].y, e);
    v[k].z = fmaxf(v[k].z, e);
    v[k].w = fmaxf(v[k].w, e);
    tail = fmaxf(tail, tot[k]);
  }

  // Coalesced stores: instruction k writes float4s [64k, 64k+64) -> 1 KiB/instr.
#pragma unroll
  for (int k = 0; k < CHUNKS; ++k) rout[LANES * k + lane] = v[k];
}

extern "C" void kernel_launch(void* const* d_in, const int* in_sizes, int n_in,
                              void* d_out, int out_size, void* d_ws, size_t ws_size,
                              hipStream_t stream) {
  const float* x = (const float*)d_in[0];
  float* out = (float*)d_out;
  const int nrows = out_size / ROW_W;  // 16384
  const int blocks = (nrows + WAVES_PER_BLOCK - 1) / WAVES_PER_BLOCK;
  suffix_max_kernel<<<blocks, 256, 0, stream>>>(x, out, nrows);
}